// Round 10
// baseline (152.094 us; speedup 1.0000x reference)
//
#include <hip/hip_runtime.h>
#include <hip/hip_fp16.h>
#include <stdint.h>

// BATCH=4096, LENGTH=128, FEAT=4, RANK=64, 126 mid sites.
#define NSITES 126
#define NUNITS (NSITES * 4)   // 504 quarter-site units, 8 frags (8 KB) each
#define XP 516                // xh row pitch in halfs (1032 B)

typedef _Float16 half8_t  __attribute__((ext_vector_type(8)));
typedef _Float16 half4_t  __attribute__((ext_vector_type(4)));
typedef float    float4_t __attribute__((ext_vector_type(4)));

#define WAITV(N) asm volatile("s_waitcnt vmcnt(" #N ")" ::: "memory")
#define TIE8(P) asm volatile("" : "+v"((P)[0]), "+v"((P)[1]), "+v"((P)[2]), "+v"((P)[3]), \
                                  "+v"((P)[4]), "+v"((P)[5]), "+v"((P)[6]), "+v"((P)[7]))

// Column permutation: tile (u,i) puts m-row m at G-column 64i + rho(u,m);
// chosen so each lane's D-regs after a site ARE the next site's B-frag
// elements (validated end-to-end in R4: absmax 3.32e35).
__device__ __forceinline__ constexpr int rho_map(int u, int m) {
    return 32*(u>>1) + 8*(m>>2) + 4*(u&1) + (m&3);
}

// volatile asm load: compiler cannot sink/remat it (R3/R5 lesson)
__device__ __forceinline__ void aload(half8_t& d, uint32_t voff, uint64_t sbase) {
    asm volatile("global_load_dwordx4 %0, %1, %2 offset:0"
                 : "=v"(d) : "v"(voff), "s"(sbase));
}

// ---------------------------------------------------------------------------
// Repack mid_cores fp32 [126][64][256] -> fp16 A-fragments (G in the A slot),
// unit order: frag f = u*8 + i*2 + h; lane(q,c) elem j =
//   G[l = 32h + 8q + j][n = 64i + rho(u,c)]        (R4 verbatim)
// ---------------------------------------------------------------------------
__global__ __launch_bounds__(256) void repack_g(const float* __restrict__ mid,
                                                _Float16* __restrict__ gt) {
    __shared__ float lds[64 * 260];
    const int s = blockIdx.x, t = threadIdx.x;
    const float* src = mid + (size_t)s * 16384;
#pragma unroll
    for (int k = 0; k < 16; ++k) {
        const int f4 = t + 256 * k;
        const int l = f4 >> 6, n0 = (f4 & 63) * 4;
        *(float4_t*)&lds[l * 260 + n0] = *(const float4_t*)&src[f4 * 4];
    }
    __syncthreads();
    half8_t* dst = (half8_t*)gt + (size_t)s * 2048;
#pragma unroll
    for (int m = 0; m < 8; ++m) {
        const int F = t + 256 * m;
        const int lane = F & 63, f = F >> 6;
        const int u = f >> 3, i = (f >> 1) & 3, h = f & 1;
        const int q = lane >> 4, c = lane & 15;
        const int n = 64 * i + rho_map(u, c);
        half8_t o;
#pragma unroll
        for (int j = 0; j < 8; ++j)
            o[j] = (_Float16)lds[(32 * h + 8 * q + j) * 260 + n];
        dst[F] = o;
    }
}

// ---------------------------------------------------------------------------
// Barrier-free chain at QUARTER-SITE granularity: 256 blocks x 64 threads,
// wave owns 16 batches end-to-end. 3 rotating 8-frag buffers (96 VGPRs —
// the scale R5 proved the compiler keeps in registers; R8/R9's 2x32-frag
// arrays fell to scratch and the async asm-load write-back corrupted them).
// Pipeline: LOADU(m+2) -> UNIT(m) with WAITV(16); 12-unit unrolled body so
// buffer choice and u are compile-time constants everywhere.
// ---------------------------------------------------------------------------
__global__ __launch_bounds__(64, 1) void tt_chain(
    const float* __restrict__ x,      // [4096][128][4]
    const float* __restrict__ first,  // [4][64]
    const float* __restrict__ last,   // [64][4]
    const _Float16* __restrict__ gt,  // frag-ordered fp16, 8 KB/unit
    float* __restrict__ out) {        // [4096]

    __shared__ _Float16 xh[16 * XP];  // fp16 x, [batch][site*4]

    const int lane = threadIdx.x;
    const int q = lane >> 4, c = lane & 15;
    const int b0 = blockIdx.x * 16;

    // stage x rows b0..b0+15 as fp16 (scalar RTN casts)
    {
        const float4_t* src = (const float4_t*)(x + (size_t)b0 * 512);
#pragma unroll
        for (int t = 0; t < 32; ++t) {
            const int idx = lane + 64 * t;           // 0..2047
            const int bb = idx >> 7, col = idx & 127;
            const float4_t v = src[idx];
            half4_t hv = { (_Float16)v.x, (_Float16)v.y,
                           (_Float16)v.z, (_Float16)v.w };
            *(half4_t*)&xh[bb * XP + col * 4] = hv;
        }
    }
    // single wave: compiler's own lgkm waits order ds_write -> ds_read

    // v0[b=c, rho(u,4q+jj)] in fp32 regs (exact fp32 x from global)
    float4_t accv0, accv1, accv2, accv3;
    {
        const float* xr = x + (size_t)(b0 + c) * 512;
        const float xi0 = xr[0], xi1 = xr[1], xi2 = xr[2], xi3 = xr[3];
        float4_t* avp[4] = { &accv0, &accv1, &accv2, &accv3 };
#pragma unroll
        for (int u = 0; u < 4; ++u)
#pragma unroll
            for (int jj = 0; jj < 4; ++jj) {
                const int r = rho_map(u, 4 * q + jj);
                (*avp[u])[jj] = xi0 * first[r] + xi1 * first[64 + r] +
                                xi2 * first[128 + r] + xi3 * first[192 + r];
            }
    }

    half8_t F0[8], F1[8], F2[8];
    half8_t bf[8];
    uint32_t voff[8];
#pragma unroll
    for (int k = 0; k < 8; ++k) voff[k] = k * 1024 + lane * 16;

    auto LOADU = [&](int m, half8_t* F) {   // unit m: 8 KB at gt + m*8192
        const uint64_t sb = (uint64_t)gt + (uint32_t)m * 8192u;
#pragma unroll
        for (int k = 0; k < 8; ++k) aload(F[k], voff[k], sb);
    };

    int e0 = 0;
    half4_t xnext = *(const half4_t*)&xh[c * XP + 1 * 4];  // x[b=c, site 1]

    LOADU(0, F0);   // outstanding 8
    LOADU(1, F1);   // outstanding 16

#define MFMA_F16 __builtin_amdgcn_mfma_f32_16x16x32_f16
#define UNIT(S, F, U, ACC) do {                                               \
    WAITV(16);                                                                \
    TIE8(F);                                                                  \
    if ((U) == 0) {   /* site start: build bf from v_S (in accv*) */          \
        const half4_t xcur = xnext;                                           \
        const int sn_ = ((S) + 2 < 128) ? (S) + 2 : 127;                      \
        xnext = *(const half4_t*)&xh[c * XP + sn_ * 4];                       \
        half8_t vh0, vh1;                                                     \
        _Pragma("unroll") for (int jj = 0; jj < 4; ++jj) {                    \
            vh0[jj]     = (_Float16)accv0[jj];                                \
            vh0[4 + jj] = (_Float16)accv1[jj];                                \
            vh1[jj]     = (_Float16)accv2[jj];                                \
            vh1[4 + jj] = (_Float16)accv3[jj];                                \
        }                                                                     \
        _Pragma("unroll") for (int i = 0; i < 4; ++i) {                       \
            half8_t sp;                                                       \
            _Pragma("unroll") for (int j = 0; j < 8; ++j) sp[j] = xcur[i];    \
            bf[i * 2 + 0] = vh0 * sp;                                         \
            bf[i * 2 + 1] = vh1 * sp;                                         \
        }                                                                     \
    }                                                                         \
    {                                                                         \
        float4_t a0_ = {0.f, 0.f, 0.f, 0.f}, a1_ = {0.f, 0.f, 0.f, 0.f};      \
        a0_ = MFMA_F16((F)[0], bf[0], a0_, 0, 0, 0);                          \
        a1_ = MFMA_F16((F)[1], bf[1], a1_, 0, 0, 0);                          \
        a0_ = MFMA_F16((F)[2], bf[2], a0_, 0, 0, 0);                          \
        a1_ = MFMA_F16((F)[3], bf[3], a1_, 0, 0, 0);                          \
        a0_ = MFMA_F16((F)[4], bf[4], a0_, 0, 0, 0);                          \
        a1_ = MFMA_F16((F)[5], bf[5], a1_, 0, 0, 0);                          \
        a0_ = MFMA_F16((F)[6], bf[6], a0_, 0, 0, 0);                          \
        a1_ = MFMA_F16((F)[7], bf[7], a1_, 0, 0, 0);                          \
        ACC = a0_ + a1_;                                                      \
    }                                                                         \
    if ((U) == 3 && ((((S) + 1) & 7) == 0)) {   /* per-batch pow2 renorm */   \
        float m_ = 0.f;                                                       \
        _Pragma("unroll") for (int jj = 0; jj < 4; ++jj) {                    \
            m_ = fmaxf(m_, fabsf(accv0[jj])); m_ = fmaxf(m_, fabsf(accv1[jj]));\
            m_ = fmaxf(m_, fabsf(accv2[jj])); m_ = fmaxf(m_, fabsf(accv3[jj]));\
        }                                                                     \
        m_ = fmaxf(m_, __shfl_xor(m_, 16));                                   \
        m_ = fmaxf(m_, __shfl_xor(m_, 32));                                   \
        int e_ = 0;                                                           \
        if (m_ > 0.f) frexpf(m_, &e_);                                        \
        const float sc_ = ldexpf(1.f, -e_);                                   \
        accv0 *= sc_; accv1 *= sc_; accv2 *= sc_; accv3 *= sc_;               \
        e0 += e_;                                                             \
    }                                                                         \
} while (0)

    for (int t = 0; t < NUNITS; t += 12) {
        const int s0 = t >> 2;
        LOADU(t + 2,  F2);  UNIT(s0,     F0, 0, accv0);
        LOADU(t + 3,  F0);  UNIT(s0,     F1, 1, accv1);
        LOADU(t + 4,  F1);  UNIT(s0,     F2, 2, accv2);
        LOADU(t + 5,  F2);  UNIT(s0,     F0, 3, accv3);
        LOADU(t + 6,  F0);  UNIT(s0 + 1, F1, 0, accv0);
        LOADU(t + 7,  F1);  UNIT(s0 + 1, F2, 1, accv1);
        LOADU(t + 8,  F2);  UNIT(s0 + 1, F0, 2, accv2);
        LOADU(t + 9,  F0);  UNIT(s0 + 1, F1, 3, accv3);
        LOADU(t + 10, F1);  UNIT(s0 + 2, F2, 0, accv0);
        LOADU(t + 11, F2);  UNIT(s0 + 2, F0, 1, accv1);
        const int m1 = (t + 12 < NUNITS) ? t + 12 : NUNITS - 1;
        const int m2 = (t + 13 < NUNITS) ? t + 13 : NUNITS - 1;
        LOADU(m1, F0);      UNIT(s0 + 2, F1, 2, accv2);
        LOADU(m2, F1);      UNIT(s0 + 2, F2, 3, accv3);
    }
    WAITV(0);   // drain the two clamped tail loads

    // epilogue: out[b] = 2^e0 * sum_r v126[b][r] * (sum_i last[r][i] x[b][127][i])
    {
        const float4_t xl = *(const float4_t*)(x + (size_t)(b0 + c) * 512 + 508);
        const float4_t* avp[4] = { &accv0, &accv1, &accv2, &accv3 };
        float dot = 0.f;
#pragma unroll
        for (int u = 0; u < 4; ++u)
#pragma unroll
            for (int jj = 0; jj < 4; ++jj) {
                const int r = rho_map(u, 4 * q + jj);
                const float4_t lr = *(const float4_t*)&last[r * 4];
                dot += (*avp[u])[jj] *
                       (lr[0] * xl[0] + lr[1] * xl[1] + lr[2] * xl[2] + lr[3] * xl[3]);
            }
        dot += __shfl_xor(dot, 16);
        dot += __shfl_xor(dot, 32);
        if (lane < 16) out[b0 + lane] = ldexpf(dot, e0);
    }
}

extern "C" void kernel_launch(void* const* d_in, const int* in_sizes, int n_in,
                              void* d_out, int out_size, void* d_ws, size_t ws_size,
                              hipStream_t stream) {
    (void)in_sizes; (void)n_in; (void)out_size; (void)ws_size;
    const float* x     = (const float*)d_in[0];
    const float* first = (const float*)d_in[1];
    const float* mid   = (const float*)d_in[2];
    const float* last  = (const float*)d_in[3];
    float* out = (float*)d_out;
    _Float16* gt = (_Float16*)d_ws;   // 126*32768 B = 4,128,768 B

    repack_g<<<126, 256, 0, stream>>>(mid, gt);
    tt_chain<<<256, 64, 0, stream>>>(x, first, last, gt, out);
}